// Round 11
// baseline (405.832 us; speedup 1.0000x reference)
//
#include <hip/hip_runtime.h>

#define D 256
#define TQ 32
#define NBW 3136   // bitmask words (padded): 100000 bits -> 3125, pad to 3136

typedef __attribute__((ext_vector_type(8))) short short8;
typedef __attribute__((ext_vector_type(4))) short short4v;
typedef __attribute__((ext_vector_type(4))) float f32x4;

__device__ __forceinline__ unsigned short f2bf(float x) {
    unsigned int u = __float_as_uint(x);
    unsigned int r = (u + 0x7FFFu + ((u >> 16) & 1u)) >> 16;   // RNE
    return (unsigned short)r;
}
__device__ __forceinline__ float bf2f(unsigned short h) {
    return __uint_as_float(((unsigned int)h) << 16);
}

// ---------------- converts ----------------

__global__ __launch_bounds__(256) void convert_emb(
    const float4* __restrict__ emb, short8* __restrict__ embbf, int total8)
{
    int stride = gridDim.x * 256;
    for (int i = blockIdx.x * 256 + threadIdx.x; i < total8; i += stride) {
        float4 v0 = emb[(size_t)i * 2 + 0];
        float4 v1 = emb[(size_t)i * 2 + 1];
        short8 p;
        p[0] = (short)f2bf(v0.x); p[1] = (short)f2bf(v0.y);
        p[2] = (short)f2bf(v0.z); p[3] = (short)f2bf(v0.w);
        p[4] = (short)f2bf(v1.x); p[5] = (short)f2bf(v1.y);
        p[6] = (short)f2bf(v1.z); p[7] = (short)f2bf(v1.w);
        embbf[i] = p;
    }
}

__global__ __launch_bounds__(256) void convert_w(
    const float* __restrict__ W, unsigned short* __restrict__ Wbf)
{
    int i = blockIdx.x * 256 + threadIdx.x;
    const float4* src = (const float4*)W + (size_t)i * 2;
    float4 v0 = src[0];
    float4 v1 = src[1];
    short8 p;
    p[0] = (short)f2bf(v0.x); p[1] = (short)f2bf(v0.y);
    p[2] = (short)f2bf(v0.z); p[3] = (short)f2bf(v0.w);
    p[4] = (short)f2bf(v1.x); p[5] = (short)f2bf(v1.y);
    p[6] = (short)f2bf(v1.z); p[7] = (short)f2bf(v1.w);
    *((short8*)Wbf + i) = p;
}

// ---------------- CSR build ----------------

__global__ __launch_bounds__(256) void flag_bits(
    const int* __restrict__ nid, unsigned int* __restrict__ bits, int Q)
{
    int q = blockIdx.x * 256 + threadIdx.x;
    if (q < Q) {
        int v = nid[q];
        atomicOr(&bits[v >> 5], 1u << (v & 31));
    }
}

__global__ __launch_bounds__(256) void hist_kernel(
    const int* __restrict__ edst, const unsigned int* __restrict__ bits,
    int* __restrict__ counts, int E)
{
    __shared__ unsigned int lb[NBW];
    for (int i = threadIdx.x; i < NBW; i += 256) lb[i] = bits[i];
    __syncthreads();
    int stride = gridDim.x * 256;
    for (int e = blockIdx.x * 256 + threadIdx.x; e < E; e += stride) {
        int d = edst[e];
        if ((lb[d >> 5] >> (d & 31)) & 1u) atomicAdd(&counts[d], 1);
    }
}

__global__ __launch_bounds__(256) void alloc_kernel(
    const int* __restrict__ counts, int* __restrict__ base,
    int* __restrict__ pos, int* __restrict__ total, int N)
{
    int n = blockIdx.x * 256 + threadIdx.x;
    if (n >= N) return;
    int c = counts[n];
    int b = 0;
    if (c > 0) b = atomicAdd(total, c);
    base[n] = b;
    pos[n]  = b;
}

__global__ __launch_bounds__(256) void bucket_kernel(
    const int* __restrict__ esrc, const int* __restrict__ edst,
    const float* __restrict__ ew, const unsigned int* __restrict__ bits,
    int* __restrict__ pos, int2* __restrict__ bucket, int E)
{
    __shared__ unsigned int lb[NBW];
    for (int i = threadIdx.x; i < NBW; i += 256) lb[i] = bits[i];
    __syncthreads();
    int stride = gridDim.x * 256;
    for (int e = blockIdx.x * 256 + threadIdx.x; e < E; e += stride) {
        int d = edst[e];
        if ((lb[d >> 5] >> (d & 31)) & 1u) {
            int idx = atomicAdd(&pos[d], 1);
            bucket[idx] = make_int2(esrc[e], __float_as_int(ew[e]));
        }
    }
}

// One wave per node; lane owns 4 bf16 elems (8B) of the 512B row.
__global__ __launch_bounds__(256) void accum_nodes(
    const short4v* __restrict__ embbf,   // [N][64] short4 (bf16)
    const int2*    __restrict__ bucket,
    const int*     __restrict__ base,
    const int*     __restrict__ counts,
    const unsigned int* __restrict__ bits,
    short4v*       __restrict__ aggbf,   // [N][64] short4 (bf16)
    int N)
{
    const int lane = threadIdx.x & 63;
    const int wid  = (int)((blockIdx.x * 256 + threadIdx.x) >> 6);
    if (wid >= N) return;
    if (!((bits[wid >> 5] >> (wid & 31)) & 1u)) return;

    const int b = base[wid];
    const int c = counts[wid];
    float a0 = 0.f, a1 = 0.f, a2 = 0.f, a3 = 0.f;

    int i = 0;
    for (; i + 8 <= c; i += 8) {
        #pragma unroll
        for (int u = 0; u < 8; ++u) {
            int2 s = bucket[b + i + u];
            short4v v = embbf[(size_t)s.x * 64 + lane];
            float w = __int_as_float(s.y);
            a0 += bf2f((unsigned short)v[0]) * w;
            a1 += bf2f((unsigned short)v[1]) * w;
            a2 += bf2f((unsigned short)v[2]) * w;
            a3 += bf2f((unsigned short)v[3]) * w;
        }
    }
    for (; i < c; ++i) {
        int2 s = bucket[b + i];
        short4v v = embbf[(size_t)s.x * 64 + lane];
        float w = __int_as_float(s.y);
        a0 += bf2f((unsigned short)v[0]) * w;
        a1 += bf2f((unsigned short)v[1]) * w;
        a2 += bf2f((unsigned short)v[2]) * w;
        a3 += bf2f((unsigned short)v[3]) * w;
    }
    short4v o;
    o[0] = (short)f2bf(a0); o[1] = (short)f2bf(a1);
    o[2] = (short)f2bf(a2); o[3] = (short)f2bf(a3);
    aggbf[(size_t)wid * 64 + lane] = o;
}

// ---------------- Phase 2 (MFMA, LDS-free, 4x wave parallelism) ----------------
// Block = 4 waves, one 16-row group per block (rg = blockIdx.x). Wave `part`
// computes columns part*64 .. part*64+63 (4 jt-tiles). A-frag gathered
// DIRECTLY from global: lane (lrow,kg) reads aggbf[nid[rg*16+lrow]]*256 +
// ks*32 + kg*8 (16B). 4 waves re-read the same 16 A-rows -> L1 hits.
// 12500 waves total (~49/CU) vs 3128 before: latency hidden by TLP.
__global__ __launch_bounds__(256) void gather_gemm_mfma(
    const unsigned short* __restrict__ aggbf,  // [N][256] bf16
    const int* __restrict__ nid,
    const unsigned short* __restrict__ Wbf,    // [256 j][256 k] bf16
    const float* __restrict__ b,
    float* __restrict__ out, int Q)
{
    const int lane = threadIdx.x & 63;
    const int part = threadIdx.x >> 6;       // wave in block = column part 0..3
    const int rg   = blockIdx.x;             // 16-row group
    const int lrow = lane & 15;
    const int kg   = lane >> 4;

    const int qa = rg * 16 + lrow;           // A-row this lane gathers
    int node = 0;
    if (qa < Q) node = nid[qa];
    const unsigned short* ap = aggbf + (size_t)node * 256 + kg * 8;

    short8 afrag[8];
    #pragma unroll
    for (int ks = 0; ks < 8; ++ks)
        afrag[ks] = *(const short8*)(ap + ks * 32);

    const unsigned short* wp0 = Wbf + (size_t)lrow * 256 + kg * 8;

    #pragma unroll
    for (int jj = 0; jj < 4; ++jj) {
        const int jt = part * 4 + jj;
        f32x4 acc = {0.f, 0.f, 0.f, 0.f};
        const unsigned short* wp = wp0 + (size_t)jt * 16 * 256;
        #pragma unroll
        for (int ks = 0; ks < 8; ++ks) {
            short8 bfrag = *(const short8*)(wp + ks * 32);
            acc = __builtin_amdgcn_mfma_f32_16x16x32_bf16(afrag[ks], bfrag, acc, 0, 0, 0);
        }
        const float bias = b[jt * 16 + lrow];
        #pragma unroll
        for (int r = 0; r < 4; ++r) {
            const int row = kg * 4 + r;              // C row in 16x16 tile
            const int oq  = rg * 16 + row;
            if (oq < Q) out[(size_t)oq * D + jt * 16 + lrow] = acc[r] + bias;
        }
    }
}

// ---------------- Fallback (small ws): f32 atomics + f32 GEMM ----------------

__global__ __launch_bounds__(256) void scatter_edges(
    const float4* __restrict__ emb, const int* __restrict__ esrc,
    const int* __restrict__ edst, const float* __restrict__ ew,
    float* __restrict__ agg, int E)
{
    const int lane = threadIdx.x & 63;
    const int wid  = (int)((blockIdx.x * blockDim.x + threadIdx.x) >> 6);
    const int nw   = (int)((gridDim.x * blockDim.x) >> 6);
    for (int e = wid; e < E; e += nw) {
        const int   s = esrc[e];
        const int   d = edst[e];
        const float w = ew[e];
        float4 v = emb[(size_t)s * (D / 4) + lane];
        float* o = agg + (size_t)d * D + lane * 4;
        unsafeAtomicAdd(o + 0, v.x * w);
        unsafeAtomicAdd(o + 1, v.y * w);
        unsafeAtomicAdd(o + 2, v.z * w);
        unsafeAtomicAdd(o + 3, v.w * w);
    }
}

__global__ __launch_bounds__(256) void gather_gemm_w(
    const float* __restrict__ agg, const int* __restrict__ nid,
    const float* __restrict__ W, const float* __restrict__ b,
    float* __restrict__ out, int Q)
{
    __shared__ float fl[TQ][D];
    const int t  = threadIdx.x;
    const int q0 = blockIdx.x * TQ;

    for (int i = t; i < TQ * (D / 4); i += 256) {
        const int r = i >> 6;
        const int c = i & 63;
        const int q = q0 + r;
        float4 v = make_float4(0.f, 0.f, 0.f, 0.f);
        if (q < Q) v = ((const float4*)agg)[(size_t)nid[q] * (D / 4) + c];
        ((float4*)&fl[r][0])[c] = v;
    }
    __syncthreads();

    const int j = t;
    float acc[TQ];
    #pragma unroll
    for (int r = 0; r < TQ; ++r) acc[r] = 0.f;

    const float4* wr4 = (const float4*)(W + (size_t)j * D);
    for (int k4 = 0; k4 < D / 4; ++k4) {
        const float4 w4 = wr4[k4];
        #pragma unroll
        for (int r = 0; r < TQ; ++r) {
            const float4 f = ((const float4*)&fl[r][0])[k4];
            acc[r] += f.x * w4.x + f.y * w4.y + f.z * w4.z + f.w * w4.w;
        }
    }

    const float bias = b[j];
    #pragma unroll
    for (int r = 0; r < TQ; ++r) {
        const int q = q0 + r;
        if (q < Q) out[(size_t)q * D + j] = acc[r] + bias;
    }
}

extern "C" void kernel_launch(void* const* d_in, const int* in_sizes, int n_in,
                              void* d_out, int out_size, void* d_ws, size_t ws_size,
                              hipStream_t stream) {
    const float* emb  = (const float*)d_in[0];
    const int*   esrc = (const int*)d_in[1];
    const int*   edst = (const int*)d_in[2];
    const float* ew   = (const float*)d_in[3];
    const int*   nid  = (const int*)d_in[4];
    const float* W    = (const float*)d_in[5];
    const float* b    = (const float*)d_in[6];
    float*       out  = (float*)d_out;

    const int N = in_sizes[0] / D;   // 100000
    const int E = in_sizes[1];       // 1600000
    const int Q = in_sizes[4];       // 50000

    char* wsb = (char*)d_ws;

    size_t off_agg    = 0;                                         // bf16 agg
    size_t off_emb    = off_agg    + (size_t)N * D * 2;            // bf16 emb
    size_t off_counts = off_emb    + (size_t)N * D * 2;
    size_t off_base   = off_counts + (size_t)N * sizeof(int);
    size_t off_pos    = off_base   + (size_t)N * sizeof(int);
    size_t off_total  = off_pos    + (size_t)N * sizeof(int);
    size_t off_bits   = off_total  + 256;
    size_t off_bucket = off_bits   + (size_t)NBW * 4;
    size_t off_wbf    = off_bucket + (size_t)E * sizeof(int2);
    size_t needed     = off_wbf    + (size_t)D * D * 2;

    if (ws_size >= needed) {
        unsigned short* aggbf  = (unsigned short*)(wsb + off_agg);
        short8*         embbf  = (short8*)(wsb + off_emb);
        int*            counts = (int*)(wsb + off_counts);
        int*            basep  = (int*)(wsb + off_base);
        int*            pos    = (int*)(wsb + off_pos);
        int*            total  = (int*)(wsb + off_total);
        unsigned int*   bits   = (unsigned int*)(wsb + off_bits);
        int2*           bucket = (int2*)(wsb + off_bucket);
        unsigned short* Wbf    = (unsigned short*)(wsb + off_wbf);

        hipMemsetAsync(wsb + off_counts, 0, off_bucket - off_counts, stream);

        convert_emb  <<<2048, 256, 0, stream>>>((const float4*)emb, embbf, N * D / 8);
        convert_w    <<<32, 256, 0, stream>>>(W, Wbf);
        flag_bits    <<<(Q + 255) / 256, 256, 0, stream>>>(nid, bits, Q);
        hist_kernel  <<<2048, 256, 0, stream>>>(edst, bits, counts, E);
        alloc_kernel <<<(N + 255) / 256, 256, 0, stream>>>(counts, basep, pos, total, N);
        bucket_kernel<<<2048, 256, 0, stream>>>(esrc, edst, ew, bits, pos, bucket, E);

        int nb_acc = (int)(((size_t)N * 64 + 255) / 256);
        accum_nodes<<<nb_acc, 256, 0, stream>>>((const short4v*)embbf, bucket, basep,
                                                counts, bits, (short4v*)aggbf, N);

        const int nb = (Q + 15) / 16;   // one 16-row group per block, 4 col-parts
        gather_gemm_mfma<<<nb, 256, 0, stream>>>(aggbf, nid, Wbf, b, out, Q);
    } else {
        float* agg = (float*)wsb;
        hipMemsetAsync(agg, 0, (size_t)N * D * sizeof(float), stream);
        scatter_edges<<<2048, 256, 0, stream>>>((const float4*)emb, esrc, edst, ew, agg, E);
        const int nb = (Q + TQ - 1) / TQ;
        gather_gemm_w<<<nb, 256, 0, stream>>>(agg, nid, W, b, out, Q);
    }
}